// Round 1
// baseline (509.826 us; speedup 1.0000x reference)
//
#include <hip/hip_runtime.h>

typedef unsigned short u16;
typedef __attribute__((ext_vector_type(8))) __bf16 bf16x8;
typedef __attribute__((ext_vector_type(4))) float f32x4;

#define NB 2
#define NS 2048
#define ND 2048
#define NH 16
#define NKH 2
#define NHD 128
#define NQKV 2560
#define ATT_SCALE 0.08838834764831845f  // 1/sqrt(128)

__device__ __forceinline__ u16 f2bf(float x) {
    union { float f; unsigned u; } v; v.f = x;
    unsigned r = v.u + 0x7fffu + ((v.u >> 16) & 1u);
    return (u16)(r >> 16);
}
__device__ __forceinline__ float bf2f(u16 x) {
    union { unsigned u; float f; } v; v.u = ((unsigned)x) << 16;
    return v.f;
}

// ---------------- fp32 -> bf16 conversion (vectorized) ----------------
__global__ void cvt_kernel(const float* __restrict__ in, u16* __restrict__ out, int n4) {
    int i = blockIdx.x * 256 + threadIdx.x;
    if (i >= n4) return;
    float4 v = ((const float4*)in)[i];
    ushort4 o;
    o.x = f2bf(v.x); o.y = f2bf(v.y); o.z = f2bf(v.z); o.w = f2bf(v.w);
    ((ushort4*)out)[i] = o;
}

// ---------------- GEMM: C[M,N] = A[M,K] * B[N,K]^T (+bias) ----------------
// 128x128 tile, BK=64, 4 waves (2x2), global_load_lds w/ XOR swizzle via
// pre-swizzled global source (LDS dest stays linear), double-buffered LDS.
template<int BIAS, int OUTBF16>
__global__ __launch_bounds__(256, 2)
void gemm_bt(const u16* __restrict__ A, const u16* __restrict__ B,
             const float* __restrict__ bias, void* __restrict__ Cout,
             int M, int N, int K)
{
    __shared__ u16 lds[2][2][8192];   // [buf][A/B][128 rows x 64 bf16] = 64 KiB
    const int l = threadIdx.x & 63;
    const int w = threadIdx.x >> 6;
    const int m0 = blockIdx.x * 128, n0 = blockIdx.y * 128;
    const int wm = (w >> 1) * 64, wn = (w & 1) * 64;
    f32x4 acc[4][4] = {};

    // staging geometry: LDS byte L = inst*4096 + w*1024 + l*16 ; row = L>>7
    // row&7 == l>>3 (inst*32, w*8 are 0 mod 8) -> per-lane constant swizzle
    const int lbyte = ((l & 7) * 16) ^ ((l >> 3) << 4);

    auto stage = [&](int buf, int k0) {
        #pragma unroll
        for (int inst = 0; inst < 4; ++inst) {
            int row = inst * 32 + w * 8 + (l >> 3);
            const u16* sa = A + (size_t)(m0 + row) * K + k0 + (lbyte >> 1);
            const u16* sb = B + (size_t)(n0 + row) * K + k0 + (lbyte >> 1);
            __builtin_amdgcn_global_load_lds(
                (const __attribute__((address_space(1))) void*)sa,
                (__attribute__((address_space(3))) void*)&lds[buf][0][inst * 2048 + w * 512],
                16, 0, 0);
            __builtin_amdgcn_global_load_lds(
                (const __attribute__((address_space(1))) void*)sb,
                (__attribute__((address_space(3))) void*)&lds[buf][1][inst * 2048 + w * 512],
                16, 0, 0);
        }
    };

    auto compute = [&](int buf) {
        const char* Ab = (const char*)&lds[buf][0][0];
        const char* Bb = (const char*)&lds[buf][1][0];
        #pragma unroll
        for (int kk = 0; kk < 2; ++kk) {
            int ac2 = kk * 64 + (l >> 4) * 16;   // byte offset of k-chunk within row
            bf16x8 af[4], bfr[4];
            #pragma unroll
            for (int i = 0; i < 4; ++i) {
                int ar = wm + i * 16 + (l & 15);
                af[i] = *(const bf16x8*)(Ab + ar * 128 + (ac2 ^ ((ar & 7) << 4)));
                int br = wn + i * 16 + (l & 15);
                bfr[i] = *(const bf16x8*)(Bb + br * 128 + (ac2 ^ ((br & 7) << 4)));
            }
            #pragma unroll
            for (int i = 0; i < 4; ++i)
                #pragma unroll
                for (int j = 0; j < 4; ++j)
                    acc[i][j] = __builtin_amdgcn_mfma_f32_16x16x32_bf16(af[i], bfr[j], acc[i][j], 0, 0, 0);
        }
    };

    stage(0, 0);
    const int NT = K >> 6;
    for (int kt = 0; kt < NT; ++kt) {
        __syncthreads();                       // drains vmcnt: staged tile ready
        if (kt + 1 < NT) stage((kt + 1) & 1, (kt + 1) << 6);
        compute(kt & 1);
    }

    #pragma unroll
    for (int j = 0; j < 4; ++j) {
        int col = n0 + wn + j * 16 + (l & 15);
        float bv = BIAS ? bias[col] : 0.0f;
        #pragma unroll
        for (int i = 0; i < 4; ++i) {
            int row = m0 + wm + i * 16 + (l >> 4) * 4;
            #pragma unroll
            for (int r = 0; r < 4; ++r) {
                float v = acc[i][j][r] + bv;
                if (OUTBF16)
                    ((u16*)Cout)[(size_t)(row + r) * N + col] = f2bf(v);
                else
                    ((float*)Cout)[(size_t)(row + r) * N + col] = v;
            }
        }
    }
}

// ---------------- RoPE + scatter to attention layouts ----------------
// qkv (B*S, 2560) bf16 -> Q (B,H,S,HD) *ATT_SCALE, K (B,HK,S,HD), Vt (B,HK,HD,S)
__global__ void rope_scatter(const u16* __restrict__ qkv,
                             const float* __restrict__ cosb,
                             const float* __restrict__ sinb,
                             u16* __restrict__ Q, u16* __restrict__ Kb, u16* __restrict__ Vt)
{
    int idx = blockIdx.x * 256 + threadIdx.x;      // total NB*NS*NQKV
    int c = idx % NQKV;
    int bs = idx / NQKV;                            // b*NS + s
    int b = bs >> 11, s = bs & 2047;
    float x = bf2f(qkv[idx]);
    if (c < NH * NHD) {
        int h = c >> 7, d = c & 127;
        float cs = cosb[(size_t)bs * NHD + d];
        float sn = sinb[(size_t)bs * NHD + d];
        int pc = (c & ~127) | (d < 64 ? d + 64 : d - 64);
        float p = bf2f(qkv[(size_t)bs * NQKV + pc]);
        float v = x * cs + (d < 64 ? -p : p) * sn;
        Q[(((size_t)b * NH + h) * NS + s) * NHD + d] = f2bf(v * ATT_SCALE);
    } else if (c < (NH + NKH) * NHD) {
        int cc = c - NH * NHD;
        int kh = cc >> 7, d = cc & 127;
        float cs = cosb[(size_t)bs * NHD + d];
        float sn = sinb[(size_t)bs * NHD + d];
        int pc = (c & ~127) | (d < 64 ? d + 64 : d - 64);
        float p = bf2f(qkv[(size_t)bs * NQKV + pc]);
        float v = x * cs + (d < 64 ? -p : p) * sn;
        Kb[(((size_t)b * NKH + kh) * NS + s) * NHD + d] = f2bf(v);
    } else {
        int cc = c - (NH + NKH) * NHD;
        int kh = cc >> 7, d = cc & 127;
        Vt[(((size_t)b * NKH + kh) * NHD + d) * NS + s] = qkv[idx];
    }
}

// ---------------- causal GQA flash attention ----------------
// 1 wave / block; 16 q-rows per block; KV tiles of 32; online softmax.
__global__ __launch_bounds__(64)
void attn_fwd(const u16* __restrict__ Q, const u16* __restrict__ Kb,
              const u16* __restrict__ Vt, u16* __restrict__ Out)
{
    __shared__ u16 pl[16 * 40];                  // P tile 16x32 bf16, stride 40 (80B, 16B-aligned)
    const int l = threadIdx.x;
    const int lr = l & 15, lg = l >> 4;
    const int bid = blockIdx.x;
    const int qt = bid & 127;                    // S/16 = 128 q-tiles
    const int h = (bid >> 7) & 15;
    const int b = bid >> 11;
    const int kh = h >> 3;                       // rep = H/HK = 8
    const int q0 = qt << 4;

    const u16* Qp = Q + (((size_t)b * NH + h) * NS + q0) * NHD;
    const u16* Kp = Kb + ((size_t)b * NKH + kh) * NS * NHD;
    const u16* Vp = Vt + ((size_t)b * NKH + kh) * (size_t)NHD * NS;

    bf16x8 qf[4];
    #pragma unroll
    for (int kk = 0; kk < 4; ++kk)
        qf[kk] = *(const bf16x8*)(Qp + lr * NHD + kk * 32 + lg * 8);

    f32x4 o[8] = {};
    float m_run[4], l_run[4];
    #pragma unroll
    for (int i = 0; i < 4; ++i) { m_run[i] = -1e30f; l_run[i] = 0.f; }

    const int tmax = (q0 + 15) >> 5;
    for (int t = 0; t <= tmax; ++t) {
        const int kp0 = t << 5;
        f32x4 s0 = {}, s1 = {};
        #pragma unroll
        for (int kk = 0; kk < 4; ++kk) {
            bf16x8 kf0 = *(const bf16x8*)(Kp + (size_t)(kp0 + lr) * NHD + kk * 32 + lg * 8);
            bf16x8 kf1 = *(const bf16x8*)(Kp + (size_t)(kp0 + 16 + lr) * NHD + kk * 32 + lg * 8);
            s0 = __builtin_amdgcn_mfma_f32_16x16x32_bf16(qf[kk], kf0, s0, 0, 0, 0);
            s1 = __builtin_amdgcn_mfma_f32_16x16x32_bf16(qf[kk], kf1, s1, 0, 0, 0);
        }
        float ps0[4], ps1[4], alpha[4];
        #pragma unroll
        for (int i = 0; i < 4; ++i) {
            int qrow = q0 + lg * 4 + i;
            float v0 = (kp0 + lr > qrow) ? -1e30f : s0[i];
            float v1 = (kp0 + 16 + lr > qrow) ? -1e30f : s1[i];
            float mi = fmaxf(v0, v1);
            #pragma unroll
            for (int dd = 1; dd < 16; dd <<= 1) mi = fmaxf(mi, __shfl_xor(mi, dd));
            float mn = fmaxf(m_run[i], mi);
            alpha[i] = __expf(m_run[i] - mn);
            m_run[i] = mn;
            float p0 = __expf(v0 - mn);
            float p1 = __expf(v1 - mn);
            ps0[i] = p0; ps1[i] = p1;
            float rs = p0 + p1;
            #pragma unroll
            for (int dd = 1; dd < 16; dd <<= 1) rs += __shfl_xor(rs, dd);
            l_run[i] = l_run[i] * alpha[i] + rs;
        }
        #pragma unroll
        for (int nf = 0; nf < 8; ++nf)
            #pragma unroll
            for (int i = 0; i < 4; ++i) o[nf][i] *= alpha[i];

        __syncthreads();      // protect previous P reads before overwrite
        #pragma unroll
        for (int i = 0; i < 4; ++i) {
            pl[(lg * 4 + i) * 40 + lr]      = f2bf(ps0[i]);
            pl[(lg * 4 + i) * 40 + 16 + lr] = f2bf(ps1[i]);
        }
        __syncthreads();      // P visible
        bf16x8 pf = *(const bf16x8*)(pl + lr * 40 + lg * 8);
        #pragma unroll
        for (int nf = 0; nf < 8; ++nf) {
            bf16x8 vf = *(const bf16x8*)(Vp + (size_t)(nf * 16 + lr) * NS + kp0 + lg * 8);
            o[nf] = __builtin_amdgcn_mfma_f32_16x16x32_bf16(pf, vf, o[nf], 0, 0, 0);
        }
    }

    float inv[4];
    #pragma unroll
    for (int i = 0; i < 4; ++i) inv[i] = 1.0f / l_run[i];
    #pragma unroll
    for (int nf = 0; nf < 8; ++nf) {
        #pragma unroll
        for (int i = 0; i < 4; ++i) {
            float v = o[nf][i] * inv[i];
            int qrow = q0 + lg * 4 + i;
            Out[((size_t)(b * NS + qrow)) * (NH * NHD) + h * NHD + nf * 16 + lr] = f2bf(v);
        }
    }
}

// ---------------- host launcher ----------------
extern "C" void kernel_launch(void* const* d_in, const int* in_sizes, int n_in,
                              void* d_out, int out_size, void* d_ws, size_t ws_size,
                              hipStream_t stream)
{
    (void)in_sizes; (void)n_in; (void)out_size; (void)ws_size;
    const float* hidden = (const float*)d_in[0];
    const float* cosb   = (const float*)d_in[1];
    const float* sinb   = (const float*)d_in[2];
    const float* qkv_w  = (const float*)d_in[3];
    const float* qkv_b  = (const float*)d_in[4];
    const float* o_w    = (const float*)d_in[5];
    float* out = (float*)d_out;

    char* ws = (char*)d_ws;
    size_t off = 0;
    auto alloc = [&](size_t bytes) {
        void* p = ws + off; off += (bytes + 255) & ~(size_t)255; return p;
    };
    u16* hid_bf  = (u16*)alloc((size_t)NB * NS * ND * 2);        // reused as attn buffer later
    u16* qkvw_bf = (u16*)alloc((size_t)NQKV * ND * 2);
    u16* ow_bf   = (u16*)alloc((size_t)ND * NH * NHD * 2);
    u16* qkv     = (u16*)alloc((size_t)NB * NS * NQKV * 2);
    u16* Qb      = (u16*)alloc((size_t)NB * NH * NS * NHD * 2);
    u16* Kb      = (u16*)alloc((size_t)NB * NKH * NS * NHD * 2);
    u16* Vt      = (u16*)alloc((size_t)NB * NKH * NS * NHD * 2);
    u16* attn    = hid_bf;   // alias: hidden_bf16 dead after GEMM1

    int n1 = NB * NS * ND / 4;
    cvt_kernel<<<(n1 + 255) / 256, 256, 0, stream>>>(hidden, hid_bf, n1);
    int n2 = NQKV * ND / 4;
    cvt_kernel<<<(n2 + 255) / 256, 256, 0, stream>>>(qkv_w, qkvw_bf, n2);
    int n3 = ND * NH * NHD / 4;
    cvt_kernel<<<(n3 + 255) / 256, 256, 0, stream>>>(o_w, ow_bf, n3);

    dim3 g1(NB * NS / 128, NQKV / 128);
    gemm_bt<1, 1><<<g1, 256, 0, stream>>>(hid_bf, qkvw_bf, qkv_b, qkv, NB * NS, NQKV, ND);

    int nr = NB * NS * NQKV;
    rope_scatter<<<nr / 256, 256, 0, stream>>>(qkv, cosb, sinb, Qb, Kb, Vt);

    attn_fwd<<<NB * NH * (NS / 16), 64, 0, stream>>>(Qb, Kb, Vt, attn);

    dim3 g2(NB * NS / 128, ND / 128);
    gemm_bt<0, 0><<<g2, 256, 0, stream>>>(attn, ow_bf, nullptr, out, NB * NS, ND, NH * NHD);
}

// Round 2
// 293.146 us; speedup vs baseline: 1.7392x; 1.7392x over previous
//
#include <hip/hip_runtime.h>

typedef unsigned short u16;
typedef __attribute__((ext_vector_type(8))) __bf16 bf16x8;
typedef __attribute__((ext_vector_type(2))) __bf16 bf16x2;
typedef __attribute__((ext_vector_type(4))) float f32x4;
typedef __attribute__((ext_vector_type(16))) float f32x16;

#define NB 2
#define NS 2048
#define ND 2048
#define NH 16
#define NKH 2
#define NHD 128
#define NQKV 2560
// 1/sqrt(128) * log2(e): scores land in log2 domain -> exp2f = raw v_exp_f32
#define QSCALE (0.08838834764831845f * 1.4426950408889634f)

__device__ __forceinline__ u16 f2bf(float x) {
    union { float f; unsigned u; } v; v.f = x;
    unsigned r = v.u + 0x7fffu + ((v.u >> 16) & 1u);
    return (u16)(r >> 16);
}
__device__ __forceinline__ float bf2f(u16 x) {
    union { unsigned u; float f; } v; v.u = ((unsigned)x) << 16;
    return v.f;
}
__device__ __forceinline__ unsigned pk2(float lo, float hi_) {
    union { bf16x2 v; unsigned u; } t;
    t.v.x = (__bf16)lo; t.v.y = (__bf16)hi_;
    return t.u;
}

// ---------------- fp32 -> bf16 conversion (vectorized) ----------------
__global__ void cvt_kernel(const float* __restrict__ in, u16* __restrict__ out, int n4) {
    int i = blockIdx.x * 256 + threadIdx.x;
    if (i >= n4) return;
    float4 v = ((const float4*)in)[i];
    ushort4 o;
    o.x = f2bf(v.x); o.y = f2bf(v.y); o.z = f2bf(v.z); o.w = f2bf(v.w);
    ((ushort4*)out)[i] = o;
}

// ---------------- GEMM: C[M,N] = A[M,K] * B[N,K]^T (+bias) ----------------
template<int BIAS, int OUTBF16>
__global__ __launch_bounds__(256, 2)
void gemm_bt(const u16* __restrict__ A, const u16* __restrict__ B,
             const float* __restrict__ bias, void* __restrict__ Cout,
             int M, int N, int K)
{
    __shared__ u16 lds[2][2][8192];
    const int l = threadIdx.x & 63;
    const int w = threadIdx.x >> 6;
    const int m0 = blockIdx.x * 128, n0 = blockIdx.y * 128;
    const int wm = (w >> 1) * 64, wn = (w & 1) * 64;
    f32x4 acc[4][4] = {};

    const int lbyte = ((l & 7) * 16) ^ ((l >> 3) << 4);

    auto stage = [&](int buf, int k0) {
        #pragma unroll
        for (int inst = 0; inst < 4; ++inst) {
            int row = inst * 32 + w * 8 + (l >> 3);
            const u16* sa = A + (size_t)(m0 + row) * K + k0 + (lbyte >> 1);
            const u16* sb = B + (size_t)(n0 + row) * K + k0 + (lbyte >> 1);
            __builtin_amdgcn_global_load_lds(
                (const __attribute__((address_space(1))) void*)sa,
                (__attribute__((address_space(3))) void*)&lds[buf][0][inst * 2048 + w * 512],
                16, 0, 0);
            __builtin_amdgcn_global_load_lds(
                (const __attribute__((address_space(1))) void*)sb,
                (__attribute__((address_space(3))) void*)&lds[buf][1][inst * 2048 + w * 512],
                16, 0, 0);
        }
    };

    auto compute = [&](int buf) {
        const char* Ab = (const char*)&lds[buf][0][0];
        const char* Bb = (const char*)&lds[buf][1][0];
        #pragma unroll
        for (int kk = 0; kk < 2; ++kk) {
            int ac2 = kk * 64 + (l >> 4) * 16;
            bf16x8 af[4], bfr[4];
            #pragma unroll
            for (int i = 0; i < 4; ++i) {
                int ar = wm + i * 16 + (l & 15);
                af[i] = *(const bf16x8*)(Ab + ar * 128 + (ac2 ^ ((ar & 7) << 4)));
                int br = wn + i * 16 + (l & 15);
                bfr[i] = *(const bf16x8*)(Bb + br * 128 + (ac2 ^ ((br & 7) << 4)));
            }
            #pragma unroll
            for (int i = 0; i < 4; ++i)
                #pragma unroll
                for (int j = 0; j < 4; ++j)
                    acc[i][j] = __builtin_amdgcn_mfma_f32_16x16x32_bf16(af[i], bfr[j], acc[i][j], 0, 0, 0);
        }
    };

    stage(0, 0);
    const int NT = K >> 6;
    for (int kt = 0; kt < NT; ++kt) {
        __syncthreads();
        if (kt + 1 < NT) stage((kt + 1) & 1, (kt + 1) << 6);
        compute(kt & 1);
    }

    #pragma unroll
    for (int j = 0; j < 4; ++j) {
        int col = n0 + wn + j * 16 + (l & 15);
        float bv = BIAS ? bias[col] : 0.0f;
        #pragma unroll
        for (int i = 0; i < 4; ++i) {
            int row = m0 + wm + i * 16 + (l >> 4) * 4;
            #pragma unroll
            for (int r = 0; r < 4; ++r) {
                float v = acc[i][j][r] + bv;
                if (OUTBF16)
                    ((u16*)Cout)[(size_t)(row + r) * N + col] = f2bf(v);
                else
                    ((float*)Cout)[(size_t)(row + r) * N + col] = v;
            }
        }
    }
}

// ---------------- RoPE + scatter to attention layouts ----------------
// qkv (B*S, 2560) bf16 -> Q (B,H,S,HD)*QSCALE, K (B,HK,S,HD), Vt (B,HK,HD,S)
__global__ void rope_scatter(const u16* __restrict__ qkv,
                             const float* __restrict__ cosb,
                             const float* __restrict__ sinb,
                             u16* __restrict__ Q, u16* __restrict__ Kb, u16* __restrict__ Vt)
{
    int idx = blockIdx.x * 256 + threadIdx.x;
    int c = idx % NQKV;
    int bs = idx / NQKV;
    int b = bs >> 11, s = bs & 2047;
    float x = bf2f(qkv[idx]);
    if (c < NH * NHD) {
        int h = c >> 7, d = c & 127;
        float cs = cosb[(size_t)bs * NHD + d];
        float sn = sinb[(size_t)bs * NHD + d];
        int pc = (c & ~127) | (d < 64 ? d + 64 : d - 64);
        float p = bf2f(qkv[(size_t)bs * NQKV + pc]);
        float v = x * cs + (d < 64 ? -p : p) * sn;
        Q[(((size_t)b * NH + h) * NS + s) * NHD + d] = f2bf(v * QSCALE);
    } else if (c < (NH + NKH) * NHD) {
        int cc = c - NH * NHD;
        int kh = cc >> 7, d = cc & 127;
        float cs = cosb[(size_t)bs * NHD + d];
        float sn = sinb[(size_t)bs * NHD + d];
        int pc = (c & ~127) | (d < 64 ? d + 64 : d - 64);
        float p = bf2f(qkv[(size_t)bs * NQKV + pc]);
        float v = x * cs + (d < 64 ? -p : p) * sn;
        Kb[(((size_t)b * NKH + kh) * NS + s) * NHD + d] = f2bf(v);
    } else {
        int cc = c - (NH + NKH) * NHD;
        int kh = cc >> 7, d = cc & 127;
        Vt[(((size_t)b * NKH + kh) * NHD + d) * NS + s] = qkv[idx];
    }
}

// ---------------- causal GQA flash attention, 32x32 swapped-QK^T ----------------
// 4 waves/block, each wave owns one 32-row q-tile; KVBLK=64; softmax in-register.
// S^T layout: col = q = lane&31, row_k = (reg&3)+8*(reg>>2)+4*(lane>>5).
__global__ __launch_bounds__(256, 2)
void attn_fwd2(const u16* __restrict__ Q, const u16* __restrict__ Kb,
               const u16* __restrict__ Vt, u16* __restrict__ Out)
{
    const int l = threadIdx.x & 63;
    const int w = threadIdx.x >> 6;
    const int kidx = blockIdx.x & 15;
    const int hh = blockIdx.x >> 4;          // 0..31  (= b*16+h)
    const int h = hh & 15, b = hh >> 4;
    int t;                                   // q-tile index 0..63 (32 rows each)
    if (w == 0) t = kidx;
    else if (w == 1) t = 31 - kidx;
    else if (w == 2) t = 32 + kidx;
    else t = 63 - kidx;
    const int q0 = t << 5;
    const int kh = h >> 3;
    const int c = l & 31, hi = l >> 5;

    const u16* Qp = Q + (((size_t)b * NH + h) * NS + q0) * NHD;
    const u16* Kp = Kb + ((size_t)b * NKH + kh) * NS * NHD;
    const u16* Vp = Vt + ((size_t)b * NKH + kh) * (size_t)NHD * NS;

    // Q as B-fragments: col=q=c, k-dim=d: qf[ds] covers d = ds*16 + hi*8 + j
    bf16x8 qf[8];
    #pragma unroll
    for (int ds = 0; ds < 8; ++ds)
        qf[ds] = *(const bf16x8*)(Qp + c * NHD + ds * 16 + hi * 8);

    f32x16 o0 = {}, o1 = {}, o2 = {}, o3 = {};   // O^T? no: row=q, col=d (dt*32+c)
    float m_run = -1e30f, l_run = 0.f;

    const int nt = (t >> 1) + 1;
    for (int kt = 0; kt < nt; ++kt) {
        const int kb = kt << 6;
        const bool lastT = (kt == nt - 1);
        const bool has1 = !(lastT && !(t & 1));   // even-t last tile: upper 32 k fully masked

        f32x16 s0 = {}, s1 = {};
        #pragma unroll
        for (int ds = 0; ds < 8; ++ds) {
            bf16x8 kf0 = *(const bf16x8*)(Kp + (size_t)(kb + c) * NHD + ds * 16 + hi * 8);
            s0 = __builtin_amdgcn_mfma_f32_32x32x16_bf16(kf0, qf[ds], s0, 0, 0, 0);
        }
        if (has1) {
            #pragma unroll
            for (int ds = 0; ds < 8; ++ds) {
                bf16x8 kf1 = *(const bf16x8*)(Kp + (size_t)(kb + 32 + c) * NHD + ds * 16 + hi * 8);
                s1 = __builtin_amdgcn_mfma_f32_32x32x16_bf16(kf1, qf[ds], s1, 0, 0, 0);
            }
        }

        float sv0[16], sv1[16];
        #pragma unroll
        for (int r = 0; r < 16; ++r) { sv0[r] = s0[r]; sv1[r] = has1 ? s1[r] : -1e30f; }

        if (lastT) {   // mask the diagonal 32x32 sub-tile (st0 if t even, st1 if t odd)
            #pragma unroll
            for (int r = 0; r < 16; ++r) {
                int rr = (r & 3) + 8 * (r >> 2) + 4 * hi;
                if (!(t & 1)) { if (rr > c) sv0[r] = -1e30f; }
                else          { if (rr > c) sv1[r] = -1e30f; }
            }
        }

        float mx = -1e30f;
        #pragma unroll
        for (int r = 0; r < 16; ++r) mx = fmaxf(mx, fmaxf(sv0[r], sv1[r]));
        mx = fmaxf(mx, __shfl_xor(mx, 32));      // combine k-halves (same q col)

        // defer-max (T13): only rescale O when some row grew past THR (log2 units)
        if (__any(mx > m_run + 8.0f)) {
            float mnew = fmaxf(m_run, mx);
            float alpha = exp2f(m_run - mnew);
            m_run = mnew;
            l_run *= alpha;
            #pragma unroll
            for (int r = 0; r < 16; ++r) {
                int qr = (r & 3) + 8 * (r >> 2) + 4 * hi;
                float aR = __shfl(alpha, qr + (l & 32));   // col-domain -> row-domain
                o0[r] *= aR; o1[r] *= aR; o2[r] *= aR; o3[r] *= aR;
            }
        }

        float e0[16], e1[16];
        float ls = 0.f;
        #pragma unroll
        for (int r = 0; r < 16; ++r) {
            e0[r] = exp2f(sv0[r] - m_run);
            e1[r] = exp2f(sv1[r] - m_run);
            ls += e0[r] + e1[r];
        }
        ls += __shfl_xor(ls, 32);
        l_run += ls;

        // P -> A-fragments: lane l needs P[q=c][ks*16 + hi*8 + j], j=0..7.
        // Own regs hold k_local = (reg&3)+8*(reg>>2)+4*hi; partner half has the rest.
        bf16x8 pa[4];
        #pragma unroll
        for (int ks = 0; ks < 4; ++ks) {
            const float* pe = (ks < 2) ? e0 : e1;
            const int b8 = (ks & 1) * 8;
            unsigned A  = pk2(pe[b8 + 0], pe[b8 + 1]);
            unsigned Bq = pk2(pe[b8 + 4], pe[b8 + 5]);
            unsigned C2 = pk2(pe[b8 + 2], pe[b8 + 3]);
            unsigned D2 = pk2(pe[b8 + 6], pe[b8 + 7]);
            unsigned sA = (unsigned)__shfl_xor((int)A, 32);
            unsigned sB = (unsigned)__shfl_xor((int)Bq, 32);
            unsigned sC = (unsigned)__shfl_xor((int)C2, 32);
            unsigned sD = (unsigned)__shfl_xor((int)D2, 32);
            union { uint4 u; bf16x8 v; } cv;
            cv.u.x = hi ? sB : A;    // j0,1
            cv.u.y = hi ? sD : C2;   // j2,3
            cv.u.z = hi ? Bq : sA;   // j4,5
            cv.u.w = hi ? D2 : sC;   // j6,7
            pa[ks] = cv.v;
        }

        // PV: B = Vt fragments (col = d = dt*32+c, k = ks*16 + hi*8 + j, contiguous)
        #pragma unroll
        for (int ks = 0; ks < 4; ++ks) {
            if (ks >= 2 && !has1) continue;
            const size_t vo = (size_t)kb + ks * 16 + hi * 8;
            bf16x8 vf;
            vf = *(const bf16x8*)(Vp + (size_t)(0 * 32 + c) * NS + vo);
            o0 = __builtin_amdgcn_mfma_f32_32x32x16_bf16(pa[ks], vf, o0, 0, 0, 0);
            vf = *(const bf16x8*)(Vp + (size_t)(1 * 32 + c) * NS + vo);
            o1 = __builtin_amdgcn_mfma_f32_32x32x16_bf16(pa[ks], vf, o1, 0, 0, 0);
            vf = *(const bf16x8*)(Vp + (size_t)(2 * 32 + c) * NS + vo);
            o2 = __builtin_amdgcn_mfma_f32_32x32x16_bf16(pa[ks], vf, o2, 0, 0, 0);
            vf = *(const bf16x8*)(Vp + (size_t)(3 * 32 + c) * NS + vo);
            o3 = __builtin_amdgcn_mfma_f32_32x32x16_bf16(pa[ks], vf, o3, 0, 0, 0);
        }
    }

    const float linv = 1.0f / l_run;
    #pragma unroll
    for (int r = 0; r < 16; ++r) {
        int qr = (r & 3) + 8 * (r >> 2) + 4 * hi;
        float lr = __shfl(linv, qr + (l & 32));
        size_t base = ((size_t)(b * NS + q0 + qr)) * (NH * NHD) + h * NHD;
        Out[base + c]      = f2bf(o0[r] * lr);
        Out[base + 32 + c] = f2bf(o1[r] * lr);
        Out[base + 64 + c] = f2bf(o2[r] * lr);
        Out[base + 96 + c] = f2bf(o3[r] * lr);
    }
}

// ---------------- host launcher ----------------
extern "C" void kernel_launch(void* const* d_in, const int* in_sizes, int n_in,
                              void* d_out, int out_size, void* d_ws, size_t ws_size,
                              hipStream_t stream)
{
    (void)in_sizes; (void)n_in; (void)out_size; (void)ws_size;
    const float* hidden = (const float*)d_in[0];
    const float* cosb   = (const float*)d_in[1];
    const float* sinb   = (const float*)d_in[2];
    const float* qkv_w  = (const float*)d_in[3];
    const float* qkv_b  = (const float*)d_in[4];
    const float* o_w    = (const float*)d_in[5];
    float* out = (float*)d_out;

    char* ws = (char*)d_ws;
    size_t off = 0;
    auto alloc = [&](size_t bytes) {
        void* p = ws + off; off += (bytes + 255) & ~(size_t)255; return p;
    };
    u16* hid_bf  = (u16*)alloc((size_t)NB * NS * ND * 2);
    u16* qkvw_bf = (u16*)alloc((size_t)NQKV * ND * 2);
    u16* ow_bf   = (u16*)alloc((size_t)ND * NH * NHD * 2);
    u16* qkv     = (u16*)alloc((size_t)NB * NS * NQKV * 2);
    u16* Qb      = (u16*)alloc((size_t)NB * NH * NS * NHD * 2);
    u16* Kb      = (u16*)alloc((size_t)NB * NKH * NS * NHD * 2);
    u16* Vt      = (u16*)alloc((size_t)NB * NKH * NS * NHD * 2);
    u16* attn    = hid_bf;   // alias: hidden_bf16 dead after GEMM1

    int n1 = NB * NS * ND / 4;
    cvt_kernel<<<(n1 + 255) / 256, 256, 0, stream>>>(hidden, hid_bf, n1);
    int n2 = NQKV * ND / 4;
    cvt_kernel<<<(n2 + 255) / 256, 256, 0, stream>>>(qkv_w, qkvw_bf, n2);
    int n3 = ND * NH * NHD / 4;
    cvt_kernel<<<(n3 + 255) / 256, 256, 0, stream>>>(o_w, ow_bf, n3);

    dim3 g1(NB * NS / 128, NQKV / 128);
    gemm_bt<1, 1><<<g1, 256, 0, stream>>>(hid_bf, qkvw_bf, qkv_b, qkv, NB * NS, NQKV, ND);

    int nr = NB * NS * NQKV;
    rope_scatter<<<nr / 256, 256, 0, stream>>>(qkv, cosb, sinb, Qb, Kb, Vt);

    attn_fwd2<<<512, 256, 0, stream>>>(Qb, Kb, Vt, attn);

    dim3 g2(NB * NS / 128, ND / 128);
    gemm_bt<0, 0><<<g2, 256, 0, stream>>>(attn, ow_bf, nullptr, out, NB * NS, ND, NH * NHD);
}

// Round 3
// 221.152 us; speedup vs baseline: 2.3053x; 1.3255x over previous
//
#include <hip/hip_runtime.h>

typedef unsigned short u16;
typedef __attribute__((ext_vector_type(8))) __bf16 bf16x8;
typedef __attribute__((ext_vector_type(2))) __bf16 bf16x2;
typedef __attribute__((ext_vector_type(4))) float f32x4;
typedef __attribute__((ext_vector_type(16))) float f32x16;

#define NB 2
#define NS 2048
#define ND 2048
#define NH 16
#define NKH 2
#define NHD 128
#define NQKV 2560
// 1/sqrt(128) * log2(e): scores in log2 domain -> exp2f = raw v_exp_f32
#define QSCALE (0.08838834764831845f * 1.4426950408889634f)

#define AS1 __attribute__((address_space(1)))
#define AS3 __attribute__((address_space(3)))

__device__ __forceinline__ u16 f2bf(float x) {
    union { float f; unsigned u; } v; v.f = x;
    unsigned r = v.u + 0x7fffu + ((v.u >> 16) & 1u);
    return (u16)(r >> 16);
}
__device__ __forceinline__ float bf2f(u16 x) {
    union { unsigned u; float f; } v; v.u = ((unsigned)x) << 16;
    return v.f;
}
__device__ __forceinline__ unsigned pk2(float lo, float hi_) {
    union { bf16x2 v; unsigned u; } t;
    t.v.x = (__bf16)lo; t.v.y = (__bf16)hi_;
    return t.u;
}

// ---------------- fp32 -> bf16 conversion (vectorized) ----------------
__global__ void cvt_kernel(const float* __restrict__ in, u16* __restrict__ out, int n4) {
    int i = blockIdx.x * 256 + threadIdx.x;
    if (i >= n4) return;
    float4 v = ((const float4*)in)[i];
    ushort4 o;
    o.x = f2bf(v.x); o.y = f2bf(v.y); o.z = f2bf(v.z); o.w = f2bf(v.w);
    ((ushort4*)out)[i] = o;
}

// ---------------- GEMM: C[M,N] = A[M,K] * B[N,K]^T (+bias) ----------------
template<int BIAS, int OUTBF16>
__global__ __launch_bounds__(256, 2)
void gemm_bt(const u16* __restrict__ A, const u16* __restrict__ B,
             const float* __restrict__ bias, void* __restrict__ Cout,
             int M, int N, int K)
{
    __shared__ u16 lds[2][2][8192];
    const int l = threadIdx.x & 63;
    const int w = threadIdx.x >> 6;
    const int m0 = blockIdx.x * 128, n0 = blockIdx.y * 128;
    const int wm = (w >> 1) * 64, wn = (w & 1) * 64;
    f32x4 acc[4][4] = {};

    const int lbyte = ((l & 7) * 16) ^ ((l >> 3) << 4);

    auto stage = [&](int buf, int k0) {
        #pragma unroll
        for (int inst = 0; inst < 4; ++inst) {
            int row = inst * 32 + w * 8 + (l >> 3);
            const u16* sa = A + (size_t)(m0 + row) * K + k0 + (lbyte >> 1);
            const u16* sb = B + (size_t)(n0 + row) * K + k0 + (lbyte >> 1);
            __builtin_amdgcn_global_load_lds(
                (const AS1 void*)sa,
                (AS3 void*)&lds[buf][0][inst * 2048 + w * 512], 16, 0, 0);
            __builtin_amdgcn_global_load_lds(
                (const AS1 void*)sb,
                (AS3 void*)&lds[buf][1][inst * 2048 + w * 512], 16, 0, 0);
        }
    };

    auto compute = [&](int buf) {
        const char* Ab = (const char*)&lds[buf][0][0];
        const char* Bb = (const char*)&lds[buf][1][0];
        #pragma unroll
        for (int kk = 0; kk < 2; ++kk) {
            int ac2 = kk * 64 + (l >> 4) * 16;
            bf16x8 af[4], bfr[4];
            #pragma unroll
            for (int i = 0; i < 4; ++i) {
                int ar = wm + i * 16 + (l & 15);
                af[i] = *(const bf16x8*)(Ab + ar * 128 + (ac2 ^ ((ar & 7) << 4)));
                int br = wn + i * 16 + (l & 15);
                bfr[i] = *(const bf16x8*)(Bb + br * 128 + (ac2 ^ ((br & 7) << 4)));
            }
            #pragma unroll
            for (int i = 0; i < 4; ++i)
                #pragma unroll
                for (int j = 0; j < 4; ++j)
                    acc[i][j] = __builtin_amdgcn_mfma_f32_16x16x32_bf16(af[i], bfr[j], acc[i][j], 0, 0, 0);
        }
    };

    stage(0, 0);
    const int NT = K >> 6;
    for (int kt = 0; kt < NT; ++kt) {
        __syncthreads();
        if (kt + 1 < NT) stage((kt + 1) & 1, (kt + 1) << 6);
        compute(kt & 1);
    }

    #pragma unroll
    for (int j = 0; j < 4; ++j) {
        int col = n0 + wn + j * 16 + (l & 15);
        float bv = BIAS ? bias[col] : 0.0f;
        #pragma unroll
        for (int i = 0; i < 4; ++i) {
            int row = m0 + wm + i * 16 + (l >> 4) * 4;
            #pragma unroll
            for (int r = 0; r < 4; ++r) {
                float v = acc[i][j][r] + bv;
                if (OUTBF16)
                    ((u16*)Cout)[(size_t)(row + r) * N + col] = f2bf(v);
                else
                    ((float*)Cout)[(size_t)(row + r) * N + col] = v;
            }
        }
    }
}

// ---------------- RoPE + scatter to attention layouts ----------------
__global__ void rope_scatter(const u16* __restrict__ qkv,
                             const float* __restrict__ cosb,
                             const float* __restrict__ sinb,
                             u16* __restrict__ Q, u16* __restrict__ Kb, u16* __restrict__ Vt)
{
    int idx = blockIdx.x * 256 + threadIdx.x;
    int c = idx % NQKV;
    int bs = idx / NQKV;
    int b = bs >> 11, s = bs & 2047;
    float x = bf2f(qkv[idx]);
    if (c < NH * NHD) {
        int h = c >> 7, d = c & 127;
        float cs = cosb[(size_t)bs * NHD + d];
        float sn = sinb[(size_t)bs * NHD + d];
        int pc = (c & ~127) | (d < 64 ? d + 64 : d - 64);
        float p = bf2f(qkv[(size_t)bs * NQKV + pc]);
        float v = x * cs + (d < 64 ? -p : p) * sn;
        Q[(((size_t)b * NH + h) * NS + s) * NHD + d] = f2bf(v * QSCALE);
    } else if (c < (NH + NKH) * NHD) {
        int cc = c - NH * NHD;
        int kh = cc >> 7, d = cc & 127;
        float cs = cosb[(size_t)bs * NHD + d];
        float sn = sinb[(size_t)bs * NHD + d];
        int pc = (c & ~127) | (d < 64 ? d + 64 : d - 64);
        float p = bf2f(qkv[(size_t)bs * NQKV + pc]);
        float v = x * cs + (d < 64 ? -p : p) * sn;
        Kb[(((size_t)b * NKH + kh) * NS + s) * NHD + d] = f2bf(v);
    } else {
        int cc = c - (NH + NKH) * NHD;
        int kh = cc >> 7, d = cc & 127;
        Vt[(((size_t)b * NKH + kh) * NHD + d) * NS + s] = qkv[idx];
    }
}

// ---------------- causal GQA flash attention v3 ----------------
// Block = 4 waves x 32 consecutive q-rows (128-row group) sharing one K/V stream.
// K/V tiles (64 kv) double-buffered in LDS (global_load_lds, XOR-swizzled src).
// Swapped QK^T 32x32, softmax fully in-register. Blocks x and x+256 take q-groups
// j and 15-j (2j+2 + 32-2j = 34 tiles) for balanced CU load.
__global__ __launch_bounds__(256, 2)
void attn_fwd3(const u16* __restrict__ Q, const u16* __restrict__ Kb,
               const u16* __restrict__ Vt, u16* __restrict__ Out)
{
    __shared__ u16 kl[2][8192];   // K tile: [64 rows][128 d] bf16, 16 KB each buf
    __shared__ u16 vl[2][8192];   // V tile: [128 d][64 kv] bf16, 16 KB each buf

    const int l = threadIdx.x & 63;
    const int w = threadIdx.x >> 6;
    const int x = blockIdx.x & 255;
    const int hh = x >> 3;                    // b*16+h
    const int j8 = x & 7;
    const int grp = (blockIdx.x < 256) ? j8 : 15 - j8;
    const int h = hh & 15, b = hh >> 4;
    const int kh = h >> 3;
    const int c = l & 31, hi = l >> 5;
    const int q0 = grp * 128 + w * 32;        // this wave's 32 q-rows
    const int qend = q0 + 31;

    const u16* Qp = Q + (((size_t)b * NH + h) * NS + q0) * NHD;
    const u16* Kp = Kb + ((size_t)b * NKH + kh) * NS * NHD;
    const u16* Vp = Vt + ((size_t)b * NKH + kh) * (size_t)NHD * NS;

    // Q as B-fragments: col=q=c, k-dim=d: qf[ds] covers d = ds*16 + hi*8 + j
    bf16x8 qf[8];
    #pragma unroll
    for (int ds = 0; ds < 8; ++ds)
        qf[ds] = *(const bf16x8*)(Qp + c * NHD + ds * 16 + hi * 8);

    f32x16 o0 = {}, o1 = {}, o2 = {}, o3 = {};
    float m_run = -1e30f, l_run = 0.f;

    // stage one 64-kv K/V tile pair into buf (8 global_load_lds per wave)
    auto stage = [&](int buf, int kt) {
        const int kb = kt << 6;
        #pragma unroll
        for (int ii = 0; ii < 4; ++ii) {           // K: rows r, swizzled col chunks
            int r = w * 16 + ii * 4 + (l >> 4);
            int q = (l & 15) ^ ((ii * 4 + (l >> 4)) & 7);
            const u16* src = Kp + (size_t)(kb + r) * NHD + q * 8;
            __builtin_amdgcn_global_load_lds(
                (const AS1 void*)src,
                (AS3 void*)&kl[buf][(w * 4 + ii) * 512], 16, 0, 0);
        }
        #pragma unroll
        for (int ii = 0; ii < 4; ++ii) {           // V: rows d, swizzled kv chunks
            int jj = w * 4 + ii;
            int d = jj * 8 + (l >> 3);
            int q = (l & 7) ^ ((l >> 3) & 7);
            const u16* src = Vp + (size_t)d * NS + kb + q * 8;
            __builtin_amdgcn_global_load_lds(
                (const AS1 void*)src,
                (AS3 void*)&vl[buf][jj * 512], 16, 0, 0);
        }
    };

    const int NT = 2 * grp + 2;                    // block-uniform KV tile count
    stage(0, 0);
    __syncthreads();

    for (int kt = 0; kt < NT; ++kt) {
        const int kb = kt << 6;
        const int cur = kt & 1;
        if (kt + 1 < NT) stage(cur ^ 1, kt + 1);

        const bool do0 = (kb <= qend);             // sub-tile [kb, kb+32)
        const bool do1 = (kb + 32 <= qend);        // sub-tile [kb+32, kb+64)
        if (do0) {
            const bool diag0 = (kb == q0);
            const bool diag1 = (kb + 32 == q0);
            const char* Klb = (const char*)kl[cur];
            const char* Vlb = (const char*)vl[cur];

            f32x16 s0 = {}, s1 = {};
            #pragma unroll
            for (int ds = 0; ds < 8; ++ds) {
                bf16x8 kf0 = *(const bf16x8*)(Klb + c * 256 + ((ds * 32 + hi * 16) ^ ((c & 7) << 4)));
                s0 = __builtin_amdgcn_mfma_f32_32x32x16_bf16(kf0, qf[ds], s0, 0, 0, 0);
            }
            if (do1) {
                #pragma unroll
                for (int ds = 0; ds < 8; ++ds) {
                    bf16x8 kf1 = *(const bf16x8*)(Klb + (32 + c) * 256 + ((ds * 32 + hi * 16) ^ ((c & 7) << 4)));
                    s1 = __builtin_amdgcn_mfma_f32_32x32x16_bf16(kf1, qf[ds], s1, 0, 0, 0);
                }
            }

            float sv0[16], sv1[16];
            #pragma unroll
            for (int r = 0; r < 16; ++r) { sv0[r] = s0[r]; sv1[r] = do1 ? s1[r] : -1e30f; }

            if (diag0 || diag1) {                  // mask diagonal 32x32 sub-tile
                #pragma unroll
                for (int r = 0; r < 16; ++r) {
                    int rr = (r & 3) + 8 * (r >> 2) + 4 * hi;
                    if (diag0) { if (rr > c) sv0[r] = -1e30f; }
                    else       { if (rr > c) sv1[r] = -1e30f; }
                }
            }

            float mx = -1e30f;
            #pragma unroll
            for (int r = 0; r < 16; ++r) mx = fmaxf(mx, fmaxf(sv0[r], sv1[r]));
            mx = fmaxf(mx, __shfl_xor(mx, 32));

            if (__any(mx > m_run + 8.0f)) {        // defer-max (T13)
                float mnew = fmaxf(m_run, mx);
                float alpha = exp2f(m_run - mnew);
                m_run = mnew;
                l_run *= alpha;
                #pragma unroll
                for (int r = 0; r < 16; ++r) {
                    int qr = (r & 3) + 8 * (r >> 2) + 4 * hi;
                    float aR = __shfl(alpha, qr + (l & 32));
                    o0[r] *= aR; o1[r] *= aR; o2[r] *= aR; o3[r] *= aR;
                }
            }

            float e0[16], e1[16];
            float ls = 0.f;
            #pragma unroll
            for (int r = 0; r < 16; ++r) {
                e0[r] = exp2f(sv0[r] - m_run);
                e1[r] = exp2f(sv1[r] - m_run);
                ls += e0[r] + e1[r];
            }
            ls += __shfl_xor(ls, 32);
            l_run += ls;

            // P -> A-fragments (lane-half exchange)
            bf16x8 pa[4];
            #pragma unroll
            for (int ks = 0; ks < 4; ++ks) {
                const float* pe = (ks < 2) ? e0 : e1;
                const int b8 = (ks & 1) * 8;
                unsigned A  = pk2(pe[b8 + 0], pe[b8 + 1]);
                unsigned Bq = pk2(pe[b8 + 4], pe[b8 + 5]);
                unsigned C2 = pk2(pe[b8 + 2], pe[b8 + 3]);
                unsigned D2 = pk2(pe[b8 + 6], pe[b8 + 7]);
                unsigned sA = (unsigned)__shfl_xor((int)A, 32);
                unsigned sB = (unsigned)__shfl_xor((int)Bq, 32);
                unsigned sC = (unsigned)__shfl_xor((int)C2, 32);
                unsigned sD = (unsigned)__shfl_xor((int)D2, 32);
                union { uint4 u; bf16x8 v; } cv;
                cv.u.x = hi ? sB : A;
                cv.u.y = hi ? sD : C2;
                cv.u.z = hi ? Bq : sA;
                cv.u.w = hi ? D2 : sC;
                pa[ks] = cv.v;
            }

            // PV from LDS V tile
            #pragma unroll
            for (int ks = 0; ks < 4; ++ks) {
                if (ks >= 2 && !do1) continue;
                const int ko = (ks * 32 + hi * 16);
                bf16x8 vf;
                vf = *(const bf16x8*)(Vlb + (0 * 32 + c) * 128 + (ko ^ ((c & 7) << 4)));
                o0 = __builtin_amdgcn_mfma_f32_32x32x16_bf16(pa[ks], vf, o0, 0, 0, 0);
                vf = *(const bf16x8*)(Vlb + (1 * 32 + c) * 128 + (ko ^ ((c & 7) << 4)));
                o1 = __builtin_amdgcn_mfma_f32_32x32x16_bf16(pa[ks], vf, o1, 0, 0, 0);
                vf = *(const bf16x8*)(Vlb + (2 * 32 + c) * 128 + (ko ^ ((c & 7) << 4)));
                o2 = __builtin_amdgcn_mfma_f32_32x32x16_bf16(pa[ks], vf, o2, 0, 0, 0);
                vf = *(const bf16x8*)(Vlb + (3 * 32 + c) * 128 + (ko ^ ((c & 7) << 4)));
                o3 = __builtin_amdgcn_mfma_f32_32x32x16_bf16(pa[ks], vf, o3, 0, 0, 0);
            }
        }
        __syncthreads();                           // drains vmcnt: next tile ready
    }

    const float linv = 1.0f / l_run;
    #pragma unroll
    for (int r = 0; r < 16; ++r) {
        int qr = (r & 3) + 8 * (r >> 2) + 4 * hi;
        float lr = __shfl(linv, qr + (l & 32));
        size_t base = ((size_t)(b * NS + q0 + qr)) * (NH * NHD) + h * NHD;
        Out[base + c]      = f2bf(o0[r] * lr);
        Out[base + 32 + c] = f2bf(o1[r] * lr);
        Out[base + 64 + c] = f2bf(o2[r] * lr);
        Out[base + 96 + c] = f2bf(o3[r] * lr);
    }
}

// ---------------- host launcher ----------------
extern "C" void kernel_launch(void* const* d_in, const int* in_sizes, int n_in,
                              void* d_out, int out_size, void* d_ws, size_t ws_size,
                              hipStream_t stream)
{
    (void)in_sizes; (void)n_in; (void)out_size; (void)ws_size;
    const float* hidden = (const float*)d_in[0];
    const float* cosb   = (const float*)d_in[1];
    const float* sinb   = (const float*)d_in[2];
    const float* qkv_w  = (const float*)d_in[3];
    const float* qkv_b  = (const float*)d_in[4];
    const float* o_w    = (const float*)d_in[5];
    float* out = (float*)d_out;

    char* ws = (char*)d_ws;
    size_t off = 0;
    auto alloc = [&](size_t bytes) {
        void* p = ws + off; off += (bytes + 255) & ~(size_t)255; return p;
    };
    u16* hid_bf  = (u16*)alloc((size_t)NB * NS * ND * 2);
    u16* qkvw_bf = (u16*)alloc((size_t)NQKV * ND * 2);
    u16* ow_bf   = (u16*)alloc((size_t)ND * NH * NHD * 2);
    u16* qkv     = (u16*)alloc((size_t)NB * NS * NQKV * 2);
    u16* Qb      = (u16*)alloc((size_t)NB * NH * NS * NHD * 2);
    u16* Kb      = (u16*)alloc((size_t)NB * NKH * NS * NHD * 2);
    u16* Vt      = (u16*)alloc((size_t)NB * NKH * NS * NHD * 2);
    u16* attn    = hid_bf;   // alias: hidden_bf16 dead after GEMM1

    int n1 = NB * NS * ND / 4;
    cvt_kernel<<<(n1 + 255) / 256, 256, 0, stream>>>(hidden, hid_bf, n1);
    int n2 = NQKV * ND / 4;
    cvt_kernel<<<(n2 + 255) / 256, 256, 0, stream>>>(qkv_w, qkvw_bf, n2);
    int n3 = ND * NH * NHD / 4;
    cvt_kernel<<<(n3 + 255) / 256, 256, 0, stream>>>(o_w, ow_bf, n3);

    dim3 g1(NB * NS / 128, NQKV / 128);
    gemm_bt<1, 1><<<g1, 256, 0, stream>>>(hid_bf, qkvw_bf, qkv_b, qkv, NB * NS, NQKV, ND);

    int nr = NB * NS * NQKV;
    rope_scatter<<<nr / 256, 256, 0, stream>>>(qkv, cosb, sinb, Qb, Kb, Vt);

    attn_fwd3<<<512, 256, 0, stream>>>(Qb, Kb, Vt, attn);

    dim3 g2(NB * NS / 128, ND / 128);
    gemm_bt<0, 0><<<g2, 256, 0, stream>>>(attn, ow_bf, nullptr, out, NB * NS, ND, NH * NHD);
}